// Round 1
// baseline (819.717 us; speedup 1.0000x reference)
//
#include <hip/hip_runtime.h>
#include <stdint.h>
#include <stddef.h>

#define OBS 128
#define F1D 256
#define HD  128
#define NA  18
#define TT  128
#define BB  1024
#define NN  (TT*BB)

typedef __attribute__((ext_vector_type(8))) short short8;
typedef __attribute__((ext_vector_type(4))) float f32x4;

// ---- workspace layout (bytes) ----
// WS_W1  : [2][F1D*OBS] bf16  (af_w1, cf_w1)           131072 B
// WS_W2  : [2][HD*F1D]  bf16  (af_w2, cf_w2)           131072 B
// WS_WC  : [2][512*256] bf16  ([Wih|Whh] per branch)   524288 B
// WS_FLAG: int (1 = action buffer is int32 words, 0 = int64)
// WS_FEAT: [2][NN*HD] bf16 — features, overwritten in-place by hs
#define WS_W1   0u
#define WS_W2   131072u
#define WS_WC   262144u
#define WS_FLAG 786432u
#define WS_FEAT 787456u

__device__ __forceinline__ unsigned short f2bf(float f) {
  union { float f; uint32_t u; } v; v.f = f;
  uint32_t u = v.u;
  u += 0x7fffu + ((u >> 16) & 1u);   // RNE
  return (unsigned short)(u >> 16);
}
__device__ __forceinline__ float bf2f(uint32_t hu) {
  union { uint32_t u; float f; } v; v.u = hu << 16;
  return v.f;
}
__device__ __forceinline__ float sigm(float x) { return 1.0f / (1.0f + __expf(-x)); }
__device__ __forceinline__ float tanhf_(float x) {
  float e = __expf(-2.0f * fabsf(x));
  float t = (1.0f - e) / (1.0f + e);
  return x >= 0.0f ? t : -t;
}
__device__ __forceinline__ f32x4 mfma16(short8 a, short8 b, f32x4 c) {
  return __builtin_amdgcn_mfma_f32_16x16x32_bf16(a, b, c, 0, 0, 0);
}

// ---------------- kernel 0: param prep (f32 -> bf16, build [Wih|Whh]) ----------------
__global__ __launch_bounds__(256) void prep_kernel(
    const float* __restrict__ aw1, const float* __restrict__ cw1,
    const float* __restrict__ aw2, const float* __restrict__ cw2,
    const float* __restrict__ awih, const float* __restrict__ awhh,
    const float* __restrict__ cwih, const float* __restrict__ cwhh,
    const int* __restrict__ action,
    unsigned short* __restrict__ w1o, unsigned short* __restrict__ w2o,
    unsigned short* __restrict__ wco, int* __restrict__ flag)
{
  int bid = blockIdx.x;
  if (bid == (int)gridDim.x - 1) {
    // action dtype detection: int64 little-endian values 0..17 => all odd 32-bit words 0
    __shared__ int any;
    if (threadIdx.x == 0) any = 0;
    __syncthreads();
    int local = 0;
    for (int i = threadIdx.x; i < 4096; i += 256)
      if ((i & 1) && action[i] != 0) local = 1;
    if (local) any = 1;
    __syncthreads();
    if (threadIdx.x == 0) flag[0] = any;
    return;
  }
  int i = bid * 256 + threadIdx.x;  // 0..393215
  if (i < 65536) {                  // w1: [2][256*128]
    int br = i >> 15, j = i & 32767;
    const float* s = br ? cw1 : aw1;
    w1o[i] = f2bf(s[j]);
  } else if (i < 131072) {          // w2: [2][128*256]
    int k = i - 65536;
    int br = k >> 15, j = k & 32767;
    const float* s = br ? cw2 : aw2;
    w2o[k] = f2bf(s[j]);
  } else {                          // wcomb: [2][512 rows][256 k]  k<128: wih, k>=128: whh
    int k = i - 131072;             // 0..262143
    int br = k >> 17, j = k & 131071;
    int n = j >> 8, kk = j & 255;
    const float* wih = br ? cwih : awih;
    const float* whh = br ? cwhh : awhh;
    float v = (kk < 128) ? wih[n*128 + kk] : whh[n*128 + (kk - 128)];
    wco[k] = f2bf(v);
  }
}

// ---------------- kernel 1: feature MLP (x -> relu(LN(relu(x W1^T+b1) W2^T+b2))) ----------------
// 32 rows per WG, 256 threads (4 waves). MFMA 16x16x32 bf16.
// LDS A-tiles use XOR-chunk swizzle: element (row,k) stored at
//   row*K + (((k>>3) ^ (row&15))<<3) + (k&7)   -> conflict-free ds_read_b128 A-frags.
__global__ __launch_bounds__(256) void feat_kernel(
    const float* __restrict__ x,
    const unsigned short* __restrict__ w1g, const unsigned short* __restrict__ w2g,
    const float* __restrict__ ab1, const float* __restrict__ cb1,
    const float* __restrict__ ab2, const float* __restrict__ cb2,
    const float* __restrict__ alnw, const float* __restrict__ clnw,
    const float* __restrict__ alnb, const float* __restrict__ clnb,
    unsigned short* __restrict__ featg)
{
  int br = blockIdx.y;
  const unsigned short* w1 = w1g + (size_t)br * (F1D*OBS); // [256][128] bf16
  const unsigned short* w2 = w2g + (size_t)br * (HD*F1D);  // [128][256] bf16
  const float* b1 = br ? cb1 : ab1;
  const float* b2 = br ? cb2 : ab2;
  const float* lw = br ? clnw : alnw;
  const float* lb = br ? clnb : alnb;
  unsigned short* feat = featg + (size_t)br * NN * HD;
  int row0 = blockIdx.x * 32;

  __shared__ unsigned short xs[32*128];   // swizzled bf16 x-tile
  __shared__ unsigned short h1s[32*256];  // swizzled bf16 h1-tile
  __shared__ float fs[32*136];            // f32 pre-LN tile (pad 8)
  __shared__ float b1s[F1D];
  __shared__ float b2s[HD], lws[HD], lbs[HD];

  int tid = threadIdx.x;
  // stage x tile (32x128 f32 -> bf16, swizzled)
  const float* xp = x + (size_t)row0 * OBS;
  for (int it = 0; it < 4; ++it) {
    int e4 = tid + it*256;          // float4 idx 0..1023
    int e  = e4 * 4;
    int r  = e >> 7, k = e & 127;
    float4 v = ((const float4*)xp)[e4];
    int sw = ((k >> 3) ^ (r & 15)) << 3;
    int ad = r*128 + sw + (k & 7);
    *(uint32_t*)&xs[ad]     = (uint32_t)f2bf(v.x) | ((uint32_t)f2bf(v.y) << 16);
    *(uint32_t*)&xs[ad + 2] = (uint32_t)f2bf(v.z) | ((uint32_t)f2bf(v.w) << 16);
  }
  if (tid < F1D) b1s[tid] = b1[tid];
  if (tid < HD) { b2s[tid] = b2[tid]; lws[tid] = lw[tid]; lbs[tid] = lb[tid]; }
  __syncthreads();

  int w = tid >> 6, lane = tid & 63, q = lane >> 4, ln = lane & 15;
  int mt = w >> 1, nh = w & 1;

  // ---- G1: h1 = relu(x @ w1^T + b1), [32,256] ----
  short8 af[4];
  for (int kf = 0; kf < 4; ++kf)
    af[kf] = *(const short8*)&xs[(mt*16 + ln)*128 + ((((kf<<2)|q) ^ ln) << 3)];
  for (int nt = 0; nt < 8; ++nt) {
    int nn = nh*128 + nt*16 + ln;
    float bv = b1s[nn];
    f32x4 acc = {bv, bv, bv, bv};
    for (int kf = 0; kf < 4; ++kf) {
      short8 bf = *(const short8*)&w1[nn*OBS + kf*32 + q*8];
      acc = mfma16(af[kf], bf, acc);
    }
    for (int rg = 0; rg < 4; ++rg) {
      float v = acc[rg] > 0.0f ? acc[rg] : 0.0f;
      int rrow = mt*16 + q*4 + rg;
      int sw = ((nn >> 3) ^ (rrow & 15)) << 3;
      h1s[rrow*256 + sw + (nn & 7)] = f2bf(v);
    }
  }
  __syncthreads();

  // ---- G2: f = h1 @ w2^T + b2, [32,128] ----
  short8 ah[8];
  for (int kf = 0; kf < 8; ++kf)
    ah[kf] = *(const short8*)&h1s[(mt*16 + ln)*256 + ((((kf<<2)|q) ^ ln) << 3)];
  for (int nt = 0; nt < 4; ++nt) {
    int nn = nh*64 + nt*16 + ln;
    float bv = b2s[nn];
    f32x4 acc = {bv, bv, bv, bv};
    for (int kf = 0; kf < 8; ++kf) {
      short8 bf = *(const short8*)&w2[nn*F1D + kf*32 + q*8];
      acc = mfma16(ah[kf], bf, acc);
    }
    for (int rg = 0; rg < 4; ++rg)
      fs[(mt*16 + q*4 + rg)*136 + nn] = acc[rg];
  }
  __syncthreads();

  // ---- LN + relu + bf16 store ----
  {
    int r = tid >> 3, g = tid & 7;
    float v[16];
    float s = 0.0f, ss = 0.0f;
    for (int j4 = 0; j4 < 4; ++j4) {
      float4 vv = *(const float4*)&fs[r*136 + g*16 + j4*4];
      v[j4*4+0] = vv.x; v[j4*4+1] = vv.y; v[j4*4+2] = vv.z; v[j4*4+3] = vv.w;
      s += vv.x + vv.y + vv.z + vv.w;
      ss += vv.x*vv.x + vv.y*vv.y + vv.z*vv.z + vv.w*vv.w;
    }
    for (int m = 1; m < 8; m <<= 1) { s += __shfl_xor(s, m); ss += __shfl_xor(ss, m); }
    float mu = s * (1.0f/128.0f);
    float var = ss * (1.0f/128.0f) - mu*mu;
    float rstd = rsqrtf(var + 1e-5f);
    unsigned short ob[16];
    for (int j = 0; j < 16; ++j) {
      int k = g*16 + j;
      float t = (v[j] - mu) * rstd * lws[k] + lbs[k];
      if (t < 0.0f) t = 0.0f;
      ob[j] = f2bf(t);
    }
    unsigned short* dst = &feat[(size_t)(row0 + r)*HD + g*16];
    *(short8*)dst       = *(short8*)&ob[0];
    *(short8*)(dst + 8) = *(short8*)&ob[8];
  }
}

// ---------------- kernel 2: masked LSTM, both branches ----------------
// grid: 128 WGs = 2 branches x 64 chunks of 16 batch rows. 512 threads (8 waves).
// Wave w owns H-cols [w*16, w*16+16): its 4 MFMA tiles are gates i/f/g/o for those
// cols -> all 4 gates of a cell land in the same lane; c/h state in VGPRs.
// B-fragments ([Wih|Whh], K=256) pinned in VGPRs for the whole T loop.
// hs (bf16) is written IN-PLACE over feat (feat[t] fully consumed before overwrite;
// __syncthreads drains vmcnt so in-flight feat loads complete before stores).
__global__ __launch_bounds__(512, 2) void lstm_kernel(
    const unsigned short* __restrict__ wcg,
    const float* __restrict__ ab, const float* __restrict__ cb,
    const float* __restrict__ ah0, const float* __restrict__ ac0,
    const float* __restrict__ ch0, const float* __restrict__ cc0,
    const int* __restrict__ done,
    unsigned short* __restrict__ featg,
    float* __restrict__ dout)
{
  int bid = blockIdx.x;
  int br = bid >> 6;
  int base = (bid & 63) * 16;
  const unsigned short* wc = wcg + (size_t)br * (512*256);
  const float* bias_g = br ? cb : ab;
  const float* h0 = br ? ch0 : ah0;
  const float* c0 = br ? cc0 : ac0;
  unsigned short* hsbuf = featg + (size_t)br * NN * HD;
  float* outh = dout + (size_t)(4 + br*2) * NN;
  float* outc = dout + (size_t)(5 + br*2) * NN;

  int tid = threadIdx.x;
  int w = tid >> 6, lane = tid & 63, q = lane >> 4, ln = lane & 15;
  int n = w*16 + ln;  // this lane's H-col

  // B-frags: [gate][kf]  (gate tiles at rows gate*128 + w*16 + ln of wcomb)
  short8 bfr[4][8];
  float bias[4];
  for (int g4 = 0; g4 < 4; ++g4) {
    int gn = g4*128 + n;
    bias[g4] = bias_g[gn];
    for (int kf = 0; kf < 8; ++kf)
      bfr[g4][kf] = *(const short8*)&wc[gn*256 + kf*32 + q*8];
  }
  // state: rows q*4+rg, col n
  float hp[4], cp[4];
  for (int rg = 0; rg < 4; ++rg) {
    int r = q*4 + rg;
    hp[rg] = h0[(base + r)*HD + n];
    cp[rg] = c0[(base + r)*HD + n];
  }

  __shared__ int dls[TT*16];
  __shared__ unsigned short hlds[16*128]; // swizzled bf16 masked-h (A operand)
  __shared__ float hf[16*132];            // f32 h for coalesced hs store
  for (int i = tid; i < TT*16; i += 512)
    dls[i] = done[(i >> 4)*BB + base + (i & 15)];
  __syncthreads();

  for (int t = 0; t < TT; ++t) {
    // feat A-frags (independent of h -> issue before barrier)
    const unsigned short* fp = hsbuf + ((size_t)(t*BB + base + ln))*HD;
    short8 afr[8];
    for (int kf = 0; kf < 4; ++kf)
      afr[kf] = *(const short8*)&fp[kf*32 + q*8];
    // mask h,c; write masked h (bf16, swizzled) to LDS
    for (int rg = 0; rg < 4; ++rg) {
      int r = q*4 + rg;
      float m = 1.0f - (float)dls[t*16 + r];
      cp[rg] *= m;
      float hm = hp[rg] * m;
      int sw = ((n >> 3) ^ r) << 3;
      hlds[r*128 + sw + (n & 7)] = f2bf(hm);
    }
    __syncthreads();
    for (int kf = 0; kf < 4; ++kf)
      afr[4+kf] = *(const short8*)&hlds[ln*128 + ((((kf<<2)|q) ^ ln) << 3)];

    f32x4 a0 = {bias[0],bias[0],bias[0],bias[0]};
    f32x4 a1 = {bias[1],bias[1],bias[1],bias[1]};
    f32x4 a2 = {bias[2],bias[2],bias[2],bias[2]};
    f32x4 a3 = {bias[3],bias[3],bias[3],bias[3]};
    for (int kf = 0; kf < 8; ++kf) {
      a0 = mfma16(afr[kf], bfr[0][kf], a0);
      a1 = mfma16(afr[kf], bfr[1][kf], a1);
      a2 = mfma16(afr[kf], bfr[2][kf], a2);
      a3 = mfma16(afr[kf], bfr[3][kf], a3);
    }
    for (int rg = 0; rg < 4; ++rg) {
      float si = sigm(a0[rg]);
      float sf = sigm(a1[rg]);
      float tg = tanhf_(a2[rg]);
      float so = sigm(a3[rg]);
      float cn = sf*cp[rg] + si*tg;
      float hn = so*tanhf_(cn);
      cp[rg] = cn; hp[rg] = hn;
      hf[(q*4+rg)*132 + n] = hn;
    }
    __syncthreads();
    // coalesced hs store (bf16), in-place over feat[t]
    {
      int r = tid >> 5, k = (tid & 31)*4;
      float4 v = *(const float4*)&hf[r*132 + k];
      union { unsigned short u[4]; uint2 d; } pk;
      pk.u[0] = f2bf(v.x); pk.u[1] = f2bf(v.y); pk.u[2] = f2bf(v.z); pk.u[3] = f2bf(v.w);
      *(uint2*)&hsbuf[((size_t)(t*BB + base + r))*HD + k] = pk.d;
    }
  }
  // final states (unmasked, post-update at t=T-1)
  for (int rg = 0; rg < 4; ++rg) {
    int r = base + q*4 + rg;
    outh[r*HD + n] = hp[rg];
    outc[r*HD + n] = cp[rg];
  }
}

// ---------------- kernel 3: heads (LN -> logits/logsoftmax/entropy; LN -> value) ----------------
__global__ __launch_bounds__(256) void head_kernel(
    const unsigned short* __restrict__ hsa, const unsigned short* __restrict__ hsc,
    const float* __restrict__ alnw, const float* __restrict__ alnb,
    const float* __restrict__ ahw, const float* __restrict__ ahb,
    const float* __restrict__ clnw, const float* __restrict__ clnb,
    const float* __restrict__ chw, const float* __restrict__ chb,
    const int* __restrict__ action, const int* __restrict__ flag,
    float* __restrict__ dout)
{
  __shared__ float whs[NA*HD];
  __shared__ float hbs[NA];
  __shared__ float alws[HD], albs[HD], clws[HD], clbs[HD], cws[HD];
  __shared__ float cbs;
  int tid = threadIdx.x;
  for (int i = tid; i < NA*HD; i += 256) whs[i] = ahw[i];
  if (tid < NA) hbs[tid] = ahb[tid];
  if (tid < HD) { alws[tid]=alnw[tid]; albs[tid]=alnb[tid];
                  clws[tid]=clnw[tid]; clbs[tid]=clnb[tid]; cws[tid]=chw[tid]; }
  if (tid == 0) cbs = chb[0];
  __syncthreads();

  int rr = blockIdx.x*256 + tid;
  int fl = flag[0];
  int act = fl ? action[rr] : (int)(((const long long*)action)[rr]);
  dout[rr] = (float)act;
  if (act < 0) act = 0;
  if (act > NA-1) act = NA-1;

  uint32_t hw_[64];
  // ---- actor ----
  {
    const uint32_t* hp = (const uint32_t*)(hsa + (size_t)rr*HD);
    for (int i = 0; i < 16; ++i) *(uint4*)&hw_[i*4] = ((const uint4*)hp)[i];
    float s = 0.0f, ss = 0.0f;
    for (int i = 0; i < 64; ++i) {
      float f0 = bf2f(hw_[i] & 0xffffu), f1 = bf2f(hw_[i] >> 16);
      s += f0 + f1; ss += f0*f0 + f1*f1;
    }
    float mu = s * (1.0f/128.0f);
    float var = ss * (1.0f/128.0f) - mu*mu;
    float rstd = rsqrtf(var + 1e-5f);
    float lg[NA];
    for (int a = 0; a < NA; ++a) lg[a] = hbs[a];
    for (int i = 0; i < 64; ++i) {
      int k0 = i*2;
      float f0 = (bf2f(hw_[i] & 0xffffu) - mu)*rstd*alws[k0]   + albs[k0];
      float f1 = (bf2f(hw_[i] >> 16)     - mu)*rstd*alws[k0+1] + albs[k0+1];
      for (int a = 0; a < NA; ++a)
        lg[a] += f0*whs[a*HD + k0] + f1*whs[a*HD + k0 + 1];
    }
    float mx = lg[0];
    for (int a = 1; a < NA; ++a) mx = fmaxf(mx, lg[a]);
    float se = 0.0f;
    for (int a = 0; a < NA; ++a) se += __expf(lg[a] - mx);
    float lse = __logf(se);
    dout[(size_t)NN + rr] = lg[act] - mx - lse;
    float ent = 0.0f;
    for (int a = 0; a < NA; ++a) { float lp = lg[a] - mx - lse; ent -= __expf(lp)*lp; }
    dout[(size_t)2*NN + rr] = ent;
  }
  // ---- critic ----
  {
    const uint32_t* hp = (const uint32_t*)(hsc + (size_t)rr*HD);
    for (int i = 0; i < 16; ++i) *(uint4*)&hw_[i*4] = ((const uint4*)hp)[i];
    float s = 0.0f, ss = 0.0f;
    for (int i = 0; i < 64; ++i) {
      float f0 = bf2f(hw_[i] & 0xffffu), f1 = bf2f(hw_[i] >> 16);
      s += f0 + f1; ss += f0*f0 + f1*f1;
    }
    float mu = s * (1.0f/128.0f);
    float var = ss * (1.0f/128.0f) - mu*mu;
    float rstd = rsqrtf(var + 1e-5f);
    float v = cbs;
    for (int i = 0; i < 64; ++i) {
      int k0 = i*2;
      float f0 = (bf2f(hw_[i] & 0xffffu) - mu)*rstd*clws[k0]   + clbs[k0];
      float f1 = (bf2f(hw_[i] >> 16)     - mu)*rstd*clws[k0+1] + clbs[k0+1];
      v += f0*cws[k0] + f1*cws[k0+1];
    }
    dout[(size_t)3*NN + rr] = v;
  }
}

extern "C" void kernel_launch(void* const* d_in, const int* in_sizes, int n_in,
                              void* d_out, int out_size, void* d_ws, size_t ws_size,
                              hipStream_t stream) {
  (void)in_sizes; (void)n_in; (void)out_size; (void)ws_size;
  const float* x    = (const float*)d_in[0];
  const float* ah0  = (const float*)d_in[1];
  const float* ac0  = (const float*)d_in[2];
  const float* ch0  = (const float*)d_in[3];
  const float* cc0  = (const float*)d_in[4];
  const int*   done = (const int*)d_in[5];
  const int*   act  = (const int*)d_in[6];
  const float* aw1  = (const float*)d_in[7];
  const float* ab1  = (const float*)d_in[8];
  const float* aw2  = (const float*)d_in[9];
  const float* ab2  = (const float*)d_in[10];
  const float* aflnw= (const float*)d_in[11];
  const float* aflnb= (const float*)d_in[12];
  const float* awih = (const float*)d_in[13];
  const float* awhh = (const float*)d_in[14];
  const float* a_b  = (const float*)d_in[15];
  const float* alnw = (const float*)d_in[16];
  const float* alnb = (const float*)d_in[17];
  const float* ahw  = (const float*)d_in[18];
  const float* ahb  = (const float*)d_in[19];
  const float* cw1  = (const float*)d_in[20];
  const float* cb1  = (const float*)d_in[21];
  const float* cw2  = (const float*)d_in[22];
  const float* cb2  = (const float*)d_in[23];
  const float* cflnw= (const float*)d_in[24];
  const float* cflnb= (const float*)d_in[25];
  const float* cwih = (const float*)d_in[26];
  const float* cwhh = (const float*)d_in[27];
  const float* c_b  = (const float*)d_in[28];
  const float* clnw = (const float*)d_in[29];
  const float* clnb = (const float*)d_in[30];
  const float* chw  = (const float*)d_in[31];
  const float* chb  = (const float*)d_in[32];

  char* ws = (char*)d_ws;
  unsigned short* w1b  = (unsigned short*)(ws + WS_W1);
  unsigned short* w2b  = (unsigned short*)(ws + WS_W2);
  unsigned short* wcb  = (unsigned short*)(ws + WS_WC);
  int*            flag = (int*)(ws + WS_FLAG);
  unsigned short* featb= (unsigned short*)(ws + WS_FEAT);
  unsigned short* hsa  = featb;
  unsigned short* hsc  = featb + (size_t)NN * HD;
  float* out = (float*)d_out;

  prep_kernel<<<1537, 256, 0, stream>>>(aw1, cw1, aw2, cw2, awih, awhh, cwih, cwhh,
                                        act, w1b, w2b, wcb, flag);
  feat_kernel<<<dim3(NN/32, 2), 256, 0, stream>>>(x, w1b, w2b, ab1, cb1, ab2, cb2,
                                                  aflnw, cflnw, aflnb, cflnb, featb);
  lstm_kernel<<<128, 512, 0, stream>>>(wcb, a_b, c_b, ah0, ac0, ch0, cc0, done,
                                       featb, out);
  head_kernel<<<512, 256, 0, stream>>>(hsa, hsc, alnw, alnb, ahw, ahb,
                                       clnw, clnb, chw, chb, act, flag, out);
}

// Round 2
// 513.422 us; speedup vs baseline: 1.5966x; 1.5966x over previous
//
#include <hip/hip_runtime.h>
#include <stdint.h>
#include <stddef.h>

#define OBS 128
#define F1D 256
#define HD  128
#define NA  18
#define TT  128
#define BB  1024
#define NN  (TT*BB)

typedef __attribute__((ext_vector_type(8))) short short8;
typedef __attribute__((ext_vector_type(4))) float f32x4;

// ---- workspace layout (bytes) ----
#define WS_W1   0u
#define WS_W2   131072u
#define WS_WC   262144u
#define WS_FLAG 786432u
#define WS_FEAT 787456u

__device__ __forceinline__ unsigned short f2bf(float f) {
  union { float f; uint32_t u; } v; v.f = f;
  uint32_t u = v.u;
  u += 0x7fffu + ((u >> 16) & 1u);   // RNE
  return (unsigned short)(u >> 16);
}
__device__ __forceinline__ float bf2f(uint32_t hu) {
  union { uint32_t u; float f; } v; v.u = hu << 16;
  return v.f;
}
// fast nonlins: exp2 + rcp, no div/fabs. Overflow-safe (inf -> rcp -> 0).
__device__ __forceinline__ float fsigm(float x) {
  float e = __builtin_amdgcn_exp2f(-1.442695041f * x);
  return __builtin_amdgcn_rcpf(1.0f + e);
}
__device__ __forceinline__ float ftanh(float x) {
  float e = __builtin_amdgcn_exp2f(-2.885390082f * x);
  return __builtin_fmaf(2.0f, __builtin_amdgcn_rcpf(1.0f + e), -1.0f);
}
__device__ __forceinline__ f32x4 mfma16(short8 a, short8 b, f32x4 c) {
  return __builtin_amdgcn_mfma_f32_16x16x32_bf16(a, b, c, 0, 0, 0);
}

// ---------------- kernel 0: param prep (f32 -> bf16, build [Wih|Whh]) ----------------
__global__ __launch_bounds__(256) void prep_kernel(
    const float* __restrict__ aw1, const float* __restrict__ cw1,
    const float* __restrict__ aw2, const float* __restrict__ cw2,
    const float* __restrict__ awih, const float* __restrict__ awhh,
    const float* __restrict__ cwih, const float* __restrict__ cwhh,
    const int* __restrict__ action,
    unsigned short* __restrict__ w1o, unsigned short* __restrict__ w2o,
    unsigned short* __restrict__ wco, int* __restrict__ flag)
{
  int bid = blockIdx.x;
  if (bid == (int)gridDim.x - 1) {
    __shared__ int any;
    if (threadIdx.x == 0) any = 0;
    __syncthreads();
    int local = 0;
    for (int i = threadIdx.x; i < 4096; i += 256)
      if ((i & 1) && action[i] != 0) local = 1;
    if (local) any = 1;
    __syncthreads();
    if (threadIdx.x == 0) flag[0] = any;
    return;
  }
  int i = bid * 256 + threadIdx.x;
  if (i < 65536) {
    int br = i >> 15, j = i & 32767;
    const float* s = br ? cw1 : aw1;
    w1o[i] = f2bf(s[j]);
  } else if (i < 131072) {
    int k = i - 65536;
    int br = k >> 15, j = k & 32767;
    const float* s = br ? cw2 : aw2;
    w2o[k] = f2bf(s[j]);
  } else {
    int k = i - 131072;
    int br = k >> 17, j = k & 131071;
    int n = j >> 8, kk = j & 255;
    const float* wih = br ? cwih : awih;
    const float* whh = br ? cwhh : awhh;
    float v = (kk < 128) ? wih[n*128 + kk] : whh[n*128 + (kk - 128)];
    wco[k] = f2bf(v);
  }
}

// ---------------- kernel 1: feature MLP ----------------
// 512 threads (8 waves), 128 rows per WG as 4 x 32-row tiles. All w1/w2
// B-fragments resident in registers for the whole kernel (loaded ONCE) —
// kills the per-tile weight re-streaming from L2 that dominated R1.
__global__ __launch_bounds__(512, 2) void feat_kernel(
    const float* __restrict__ x,
    const unsigned short* __restrict__ w1g, const unsigned short* __restrict__ w2g,
    const float* __restrict__ ab1, const float* __restrict__ cb1,
    const float* __restrict__ ab2, const float* __restrict__ cb2,
    const float* __restrict__ alnw, const float* __restrict__ clnw,
    const float* __restrict__ alnb, const float* __restrict__ clnb,
    unsigned short* __restrict__ featg)
{
  int br = blockIdx.y;
  const unsigned short* w1 = w1g + (size_t)br * (F1D*OBS); // [256][128]
  const unsigned short* w2 = w2g + (size_t)br * (HD*F1D);  // [128][256]
  const float* b1 = br ? cb1 : ab1;
  const float* b2 = br ? cb2 : ab2;
  const float* lw = br ? clnw : alnw;
  const float* lb = br ? clnb : alnb;
  unsigned short* feat = featg + (size_t)br * NN * HD;

  __shared__ unsigned short xs[32*128];   // swizzled bf16 x-tile
  __shared__ unsigned short h1s[32*256];  // swizzled bf16 h1-tile
  __shared__ float fs[32*140];            // f32 pre-LN tile (pad->140: 2-way banks on write)
  __shared__ float lws[HD], lbs[HD];

  int tid = threadIdx.x;
  int w = tid >> 6, lane = tid & 63, q = lane >> 4, ln = lane & 15;

  // resident B-fragments: wave w owns G1 cols [w*32,w*32+32), G2 cols [w*16,w*16+16)
  short8 b1f[2][4]; float b1v[2];
  for (int ct = 0; ct < 2; ++ct) {
    int nn = w*32 + ct*16 + ln;
    b1v[ct] = b1[nn];
    for (int kf = 0; kf < 4; ++kf)
      b1f[ct][kf] = *(const short8*)&w1[nn*OBS + kf*32 + q*8];
  }
  short8 b2f[8]; float b2v;
  int nn2 = w*16 + ln;
  b2v = b2[nn2];
  for (int kf = 0; kf < 8; ++kf)
    b2f[kf] = *(const short8*)&w2[nn2*F1D + kf*32 + q*8];
  if (tid < HD) { lws[tid] = lw[tid]; lbs[tid] = lb[tid]; }

  for (int it = 0; it < 4; ++it) {
    int row0 = blockIdx.x * 128 + it * 32;
    const float* xp = x + (size_t)row0 * OBS;
    for (int s = 0; s < 2; ++s) {
      int e4 = tid + s*512;
      int e  = e4 * 4;
      int r  = e >> 7, k = e & 127;
      float4 v = ((const float4*)xp)[e4];
      int sw = ((k >> 3) ^ (r & 15)) << 3;
      int ad = r*128 + sw + (k & 7);
      *(uint32_t*)&xs[ad]     = (uint32_t)f2bf(v.x) | ((uint32_t)f2bf(v.y) << 16);
      *(uint32_t*)&xs[ad + 2] = (uint32_t)f2bf(v.z) | ((uint32_t)f2bf(v.w) << 16);
    }
    __syncthreads();
    // ---- G1: h1 = relu(x @ w1^T + b1) ----
    for (int mt = 0; mt < 2; ++mt) {
      short8 af[4];
      for (int kf = 0; kf < 4; ++kf)
        af[kf] = *(const short8*)&xs[(mt*16 + ln)*128 + ((((kf<<2)|q) ^ ln) << 3)];
      for (int ct = 0; ct < 2; ++ct) {
        f32x4 acc = {b1v[ct], b1v[ct], b1v[ct], b1v[ct]};
        for (int kf = 0; kf < 4; ++kf) acc = mfma16(af[kf], b1f[ct][kf], acc);
        int nn = w*32 + ct*16 + ln;
        for (int rg = 0; rg < 4; ++rg) {
          float v = acc[rg] > 0.0f ? acc[rg] : 0.0f;
          int rrow = mt*16 + q*4 + rg;
          int sw = ((nn >> 3) ^ (rrow & 15)) << 3;
          h1s[rrow*256 + sw + (nn & 7)] = f2bf(v);
        }
      }
    }
    __syncthreads();
    // ---- G2: f = h1 @ w2^T + b2 ----
    for (int mt = 0; mt < 2; ++mt) {
      short8 ah[8];
      for (int kf = 0; kf < 8; ++kf)
        ah[kf] = *(const short8*)&h1s[(mt*16 + ln)*256 + ((((kf<<2)|q) ^ ln) << 3)];
      f32x4 acc = {b2v, b2v, b2v, b2v};
      for (int kf = 0; kf < 8; ++kf) acc = mfma16(ah[kf], b2f[kf], acc);
      for (int rg = 0; rg < 4; ++rg)
        fs[(mt*16 + q*4 + rg)*140 + nn2] = acc[rg];
    }
    __syncthreads();
    // ---- LN + relu + bf16 store: 32 rows x 16 threads/row ----
    {
      int r = tid >> 4, g = tid & 15;
      float4 v0 = *(const float4*)&fs[r*140 + g*8];
      float4 v1 = *(const float4*)&fs[r*140 + g*8 + 4];
      float s  = v0.x+v0.y+v0.z+v0.w + v1.x+v1.y+v1.z+v1.w;
      float ss = v0.x*v0.x+v0.y*v0.y+v0.z*v0.z+v0.w*v0.w
               + v1.x*v1.x+v1.y*v1.y+v1.z*v1.z+v1.w*v1.w;
      for (int m = 1; m < 16; m <<= 1) { s += __shfl_xor(s, m); ss += __shfl_xor(ss, m); }
      float mu = s * (1.0f/128.0f);
      float var = ss * (1.0f/128.0f) - mu*mu;
      float rstd = rsqrtf(var + 1e-5f);
      float vv[8] = {v0.x,v0.y,v0.z,v0.w,v1.x,v1.y,v1.z,v1.w};
      unsigned short ob[8];
      for (int j = 0; j < 8; ++j) {
        int k = g*8 + j;
        float t = (vv[j] - mu) * rstd * lws[k] + lbs[k];
        ob[j] = f2bf(t > 0.0f ? t : 0.0f);
      }
      *(short8*)&feat[(size_t)(row0 + r)*HD + g*8] = *(short8*)ob;
    }
    __syncthreads();  // fs reads done before next iter's G2 rewrites (cheap insurance)
  }
}

// ---------------- kernel 2: masked LSTM, pipelined ----------------
// 128 WGs (2 branch x 64 chunks of 16 rows), 512 thr. Per step: ONE barrier,
// double-buffered h-LDS, feat[t+1] prefetched into regs during step t,
// done-mask for t+1 applied at end of step t, scatter bf16 hs stores
// (no LDS round-trip). B-frags resident (128 regs) for all 128 steps.
__global__ __launch_bounds__(512, 2) void lstm_kernel(
    const unsigned short* __restrict__ wcg,
    const float* __restrict__ ab, const float* __restrict__ cb,
    const float* __restrict__ ah0, const float* __restrict__ ac0,
    const float* __restrict__ ch0, const float* __restrict__ cc0,
    const int* __restrict__ done,
    unsigned short* __restrict__ featg,
    float* __restrict__ dout)
{
  int bid = blockIdx.x;
  int br = bid >> 6;
  int base = (bid & 63) * 16;
  const unsigned short* wc = wcg + (size_t)br * (512*256);
  const float* bias_g = br ? cb : ab;
  const float* h0 = br ? ch0 : ah0;
  const float* c0 = br ? cc0 : ac0;
  unsigned short* hsbuf = featg + (size_t)br * NN * HD;
  float* outh = dout + (size_t)(4 + br*2) * NN;
  float* outc = dout + (size_t)(5 + br*2) * NN;

  int tid = threadIdx.x;
  int w = tid >> 6, lane = tid & 63, q = lane >> 4, ln = lane & 15;
  int n = w*16 + ln;

  short8 bfr[4][8];
  float bias[4];
  for (int g4 = 0; g4 < 4; ++g4) {
    int gn = g4*128 + n;
    bias[g4] = bias_g[gn];
    for (int kf = 0; kf < 8; ++kf)
      bfr[g4][kf] = *(const short8*)&wc[gn*256 + kf*32 + q*8];
  }

  __shared__ float mls[TT*16];            // 1 - done
  __shared__ unsigned short hlds[2][16*128];
  for (int i = tid; i < TT*16; i += 512)
    mls[i] = 1.0f - (float)done[(i >> 4)*BB + base + (i & 15)];

  float hp[4], cp[4], h0v[4];
  for (int rg = 0; rg < 4; ++rg) {
    int r = q*4 + rg;
    h0v[rg] = h0[(base + r)*HD + n];
    cp[rg]  = c0[(base + r)*HD + n];
    hp[rg]  = h0v[rg];
  }
  // prefetch feat[0]
  short8 afr[4];
  {
    const unsigned short* fp = hsbuf + ((size_t)(base + ln))*HD;
    for (int kf = 0; kf < 4; ++kf)
      afr[kf] = *(const short8*)&fp[kf*32 + q*8];
  }
  __syncthreads();  // mls ready
  {
    float4 m0 = *(const float4*)&mls[q*4];
    for (int rg = 0; rg < 4; ++rg) {
      float m = (&m0.x)[rg];
      cp[rg] *= m;
      int r = q*4 + rg;
      hlds[0][r*128 + (((n >> 3) ^ r) << 3) + (n & 7)] = f2bf(h0v[rg] * m);
    }
  }
  __syncthreads();  // hlds[0] ready

  for (int t = 0; t < TT; ++t) {
    const unsigned short* hb = hlds[t & 1];
    unsigned short* hbn = hlds[(t & 1) ^ 1];
    short8 hfr[4];
    for (int kf = 0; kf < 4; ++kf)
      hfr[kf] = *(const short8*)&hb[ln*128 + ((((kf<<2)|q) ^ ln) << 3)];
    // prefetch feat[t+1] (t=127: dummy reload of row 127, result unused)
    int tn = (t < TT-1) ? t + 1 : TT-1;
    short8 nfr[4];
    {
      const unsigned short* fp = hsbuf + ((size_t)(tn*BB + base + ln))*HD;
      for (int kf = 0; kf < 4; ++kf)
        nfr[kf] = *(const short8*)&fp[kf*32 + q*8];
    }
    f32x4 a0 = {bias[0],bias[0],bias[0],bias[0]};
    f32x4 a1 = {bias[1],bias[1],bias[1],bias[1]};
    f32x4 a2 = {bias[2],bias[2],bias[2],bias[2]};
    f32x4 a3 = {bias[3],bias[3],bias[3],bias[3]};
    for (int kf = 0; kf < 4; ++kf) {
      a0 = mfma16(afr[kf], bfr[0][kf], a0);
      a1 = mfma16(afr[kf], bfr[1][kf], a1);
      a2 = mfma16(afr[kf], bfr[2][kf], a2);
      a3 = mfma16(afr[kf], bfr[3][kf], a3);
    }
    for (int kf = 0; kf < 4; ++kf) {
      a0 = mfma16(hfr[kf], bfr[0][4+kf], a0);
      a1 = mfma16(hfr[kf], bfr[1][4+kf], a1);
      a2 = mfma16(hfr[kf], bfr[2][4+kf], a2);
      a3 = mfma16(hfr[kf], bfr[3][4+kf], a3);
    }
    float4 mn;
    if (t < TT-1) mn = *(const float4*)&mls[(t+1)*16 + q*4];
    else          mn = make_float4(1.0f, 1.0f, 1.0f, 1.0f);
    for (int rg = 0; rg < 4; ++rg) {
      float si = fsigm(a0[rg]);
      float sf = fsigm(a1[rg]);
      float tg = ftanh(a2[rg]);
      float so = fsigm(a3[rg]);
      float cn = sf*cp[rg] + si*tg;
      float hn = so*ftanh(cn);
      hsbuf[((size_t)(t*BB + base + q*4 + rg))*HD + n] = f2bf(hn);  // hs[t] over feat[t]
      float m = (&mn.x)[rg];
      cp[rg] = cn * m;          // masked for step t+1 (t=127: m=1 -> final c)
      hp[rg] = hn;
      int r = q*4 + rg;
      hbn[r*128 + (((n >> 3) ^ r) << 3) + (n & 7)] = f2bf(hn * m);
    }
    __syncthreads();  // single barrier: hbn visible, hb reads retired
    for (int kf = 0; kf < 4; ++kf) afr[kf] = nfr[kf];
  }
  for (int rg = 0; rg < 4; ++rg) {
    int r = base + q*4 + rg;
    outh[r*HD + n] = hp[rg];
    outc[r*HD + n] = cp[rg];
  }
}

// ---------------- kernel 3: heads ----------------
__global__ __launch_bounds__(256) void head_kernel(
    const unsigned short* __restrict__ hsa, const unsigned short* __restrict__ hsc,
    const float* __restrict__ alnw, const float* __restrict__ alnb,
    const float* __restrict__ ahw, const float* __restrict__ ahb,
    const float* __restrict__ clnw, const float* __restrict__ clnb,
    const float* __restrict__ chw, const float* __restrict__ chb,
    const int* __restrict__ action, const int* __restrict__ flag,
    float* __restrict__ dout)
{
  __shared__ float whs[NA*HD];
  __shared__ float hbs[NA];
  __shared__ float alws[HD], albs[HD], clws[HD], clbs[HD], cws[HD];
  __shared__ float cbs;
  int tid = threadIdx.x;
  for (int i = tid; i < NA*HD; i += 256) whs[i] = ahw[i];
  if (tid < NA) hbs[tid] = ahb[tid];
  if (tid < HD) { alws[tid]=alnw[tid]; albs[tid]=alnb[tid];
                  clws[tid]=clnw[tid]; clbs[tid]=clnb[tid]; cws[tid]=chw[tid]; }
  if (tid == 0) cbs = chb[0];
  __syncthreads();

  int rr = blockIdx.x*256 + tid;
  int fl = flag[0];
  int act = fl ? action[rr] : (int)(((const long long*)action)[rr]);
  dout[rr] = (float)act;
  if (act < 0) act = 0;
  if (act > NA-1) act = NA-1;

  uint32_t hw_[64];
  // ---- actor ----
  {
    const uint32_t* hp = (const uint32_t*)(hsa + (size_t)rr*HD);
    for (int i = 0; i < 16; ++i) *(uint4*)&hw_[i*4] = ((const uint4*)hp)[i];
    float s = 0.0f, ss = 0.0f;
    for (int i = 0; i < 64; ++i) {
      float f0 = bf2f(hw_[i] & 0xffffu), f1 = bf2f(hw_[i] >> 16);
      s += f0 + f1; ss += f0*f0 + f1*f1;
    }
    float mu = s * (1.0f/128.0f);
    float var = ss * (1.0f/128.0f) - mu*mu;
    float rstd = rsqrtf(var + 1e-5f);
    float lg[NA];
    for (int a = 0; a < NA; ++a) lg[a] = hbs[a];
    for (int i = 0; i < 64; ++i) {
      int k0 = i*2;
      float f0 = (bf2f(hw_[i] & 0xffffu) - mu)*rstd*alws[k0]   + albs[k0];
      float f1 = (bf2f(hw_[i] >> 16)     - mu)*rstd*alws[k0+1] + albs[k0+1];
      for (int a = 0; a < NA; ++a)
        lg[a] += f0*whs[a*HD + k0] + f1*whs[a*HD + k0 + 1];
    }
    float mx = lg[0];
    for (int a = 1; a < NA; ++a) mx = fmaxf(mx, lg[a]);
    float se = 0.0f;
    for (int a = 0; a < NA; ++a) se += __expf(lg[a] - mx);
    float lse = __logf(se);
    dout[(size_t)NN + rr] = lg[act] - mx - lse;
    float ent = 0.0f;
    for (int a = 0; a < NA; ++a) { float lp = lg[a] - mx - lse; ent -= __expf(lp)*lp; }
    dout[(size_t)2*NN + rr] = ent;
  }
  // ---- critic ----
  {
    const uint32_t* hp = (const uint32_t*)(hsc + (size_t)rr*HD);
    for (int i = 0; i < 16; ++i) *(uint4*)&hw_[i*4] = ((const uint4*)hp)[i];
    float s = 0.0f, ss = 0.0f;
    for (int i = 0; i < 64; ++i) {
      float f0 = bf2f(hw_[i] & 0xffffu), f1 = bf2f(hw_[i] >> 16);
      s += f0 + f1; ss += f0*f0 + f1*f1;
    }
    float mu = s * (1.0f/128.0f);
    float var = ss * (1.0f/128.0f) - mu*mu;
    float rstd = rsqrtf(var + 1e-5f);
    float v = cbs;
    for (int i = 0; i < 64; ++i) {
      int k0 = i*2;
      float f0 = (bf2f(hw_[i] & 0xffffu) - mu)*rstd*clws[k0]   + clbs[k0];
      float f1 = (bf2f(hw_[i] >> 16)     - mu)*rstd*clws[k0+1] + clbs[k0+1];
      v += f0*cws[k0] + f1*cws[k0+1];
    }
    dout[(size_t)3*NN + rr] = v;
  }
}

extern "C" void kernel_launch(void* const* d_in, const int* in_sizes, int n_in,
                              void* d_out, int out_size, void* d_ws, size_t ws_size,
                              hipStream_t stream) {
  (void)in_sizes; (void)n_in; (void)out_size; (void)ws_size;
  const float* x    = (const float*)d_in[0];
  const float* ah0  = (const float*)d_in[1];
  const float* ac0  = (const float*)d_in[2];
  const float* ch0  = (const float*)d_in[3];
  const float* cc0  = (const float*)d_in[4];
  const int*   done = (const int*)d_in[5];
  const int*   act  = (const int*)d_in[6];
  const float* aw1  = (const float*)d_in[7];
  const float* ab1  = (const float*)d_in[8];
  const float* aw2  = (const float*)d_in[9];
  const float* ab2  = (const float*)d_in[10];
  const float* aflnw= (const float*)d_in[11];
  const float* aflnb= (const float*)d_in[12];
  const float* awih = (const float*)d_in[13];
  const float* awhh = (const float*)d_in[14];
  const float* a_b  = (const float*)d_in[15];
  const float* alnw = (const float*)d_in[16];
  const float* alnb = (const float*)d_in[17];
  const float* ahw  = (const float*)d_in[18];
  const float* ahb  = (const float*)d_in[19];
  const float* cw1  = (const float*)d_in[20];
  const float* cb1  = (const float*)d_in[21];
  const float* cw2  = (const float*)d_in[22];
  const float* cb2  = (const float*)d_in[23];
  const float* cflnw= (const float*)d_in[24];
  const float* cflnb= (const float*)d_in[25];
  const float* cwih = (const float*)d_in[26];
  const float* cwhh = (const float*)d_in[27];
  const float* c_b  = (const float*)d_in[28];
  const float* clnw = (const float*)d_in[29];
  const float* clnb = (const float*)d_in[30];
  const float* chw  = (const float*)d_in[31];
  const float* chb  = (const float*)d_in[32];

  char* ws = (char*)d_ws;
  unsigned short* w1b  = (unsigned short*)(ws + WS_W1);
  unsigned short* w2b  = (unsigned short*)(ws + WS_W2);
  unsigned short* wcb  = (unsigned short*)(ws + WS_WC);
  int*            flag = (int*)(ws + WS_FLAG);
  unsigned short* featb= (unsigned short*)(ws + WS_FEAT);
  unsigned short* hsa  = featb;
  unsigned short* hsc  = featb + (size_t)NN * HD;
  float* out = (float*)d_out;

  prep_kernel<<<1537, 256, 0, stream>>>(aw1, cw1, aw2, cw2, awih, awhh, cwih, cwhh,
                                        act, w1b, w2b, wcb, flag);
  feat_kernel<<<dim3(NN/128, 2), 512, 0, stream>>>(x, w1b, w2b, ab1, cb1, ab2, cb2,
                                                   aflnw, cflnw, aflnb, cflnb, featb);
  lstm_kernel<<<128, 512, 0, stream>>>(wcb, a_b, c_b, ah0, ac0, ch0, cc0, done,
                                       featb, out);
  head_kernel<<<512, 256, 0, stream>>>(hsa, hsc, alnw, alnb, ahw, ahb,
                                       clnw, clnb, chw, chb, act, flag, out);
}